// Round 6
// baseline (16.752 us; speedup 1.0000x reference)
//
#include <hip/hip_runtime.h>
#include <hip/hip_bf16.h>

// EdgePrompt: out[e] = edge_weight[e] * sigmoid( x[src[e]]·W[:d] + x[dst[e]]·W[d:] + b )
// Two launches (cooperative grid.sync was a 4.6x regression — R2 post-mortem):
//   K1: proj_src[n] = x[n]·W[:d], proj_dst[n] = x[n]·W[d:]  (into d_ws)
//       8 nodes/wave: 8 lanes/node, 64 B/lane (4x float4 NT), 3-level butterfly.
//   K2: per-edge gather + sigmoid + scale, 4 edges/thread, non-temporal streams.
// NOTE: __builtin_nontemporal_* requires clang ext_vector_type (R4 compile fail).

#define IN_DIM 128
#define BLOCK 256

typedef int   i32x4 __attribute__((ext_vector_type(4)));
typedef float f32x4 __attribute__((ext_vector_type(4)));

__device__ __forceinline__ float dot4(f32x4 a, f32x4 b) {
    return a.x * b.x + a.y * b.y + a.z * b.z + a.w * b.w;
}

// K1: 8 nodes per 64-lane wave; lane (g,sg) with g=node slot (0..7), sg=0..7.
// Each lane covers 16 of the node's 128 floats via 4 float4 loads at
// float-offset sg*4 + k*32 (per-instruction: 8 chunks of 128 B at stride 512 —
// fully coalesced cache lines).
__global__ void __launch_bounds__(BLOCK)
edgeprompt_proj(const float* __restrict__ x,
                const float* __restrict__ W,
                float* __restrict__ proj,   // [2*n_nodes]: [0,N)=src-proj, [N,2N)=dst-proj
                int n_nodes) {
    const int lane = threadIdx.x & 63;
    const int g    = lane >> 3;        // node slot within the wave (0..7)
    const int sg   = lane & 7;         // sub-lane within the 8-lane group
    const int wave = (blockIdx.x * blockDim.x + threadIdx.x) >> 6;

    // W is 1 KB, node-invariant: hoist per-lane fragments (L1-resident).
    const f32x4 ws0 = *reinterpret_cast<const f32x4*>(&W[sg * 4]);
    const f32x4 ws1 = *reinterpret_cast<const f32x4*>(&W[sg * 4 + 32]);
    const f32x4 ws2 = *reinterpret_cast<const f32x4*>(&W[sg * 4 + 64]);
    const f32x4 ws3 = *reinterpret_cast<const f32x4*>(&W[sg * 4 + 96]);
    const f32x4 wd0 = *reinterpret_cast<const f32x4*>(&W[IN_DIM + sg * 4]);
    const f32x4 wd1 = *reinterpret_cast<const f32x4*>(&W[IN_DIM + sg * 4 + 32]);
    const f32x4 wd2 = *reinterpret_cast<const f32x4*>(&W[IN_DIM + sg * 4 + 64]);
    const f32x4 wd3 = *reinterpret_cast<const f32x4*>(&W[IN_DIM + sg * 4 + 96]);

    const int n = wave * 8 + g;
    if (n >= n_nodes) return;

    const float* xr = &x[(size_t)n * IN_DIM + sg * 4];
    const f32x4 x0 = __builtin_nontemporal_load(reinterpret_cast<const f32x4*>(xr));
    const f32x4 x1 = __builtin_nontemporal_load(reinterpret_cast<const f32x4*>(xr + 32));
    const f32x4 x2 = __builtin_nontemporal_load(reinterpret_cast<const f32x4*>(xr + 64));
    const f32x4 x3 = __builtin_nontemporal_load(reinterpret_cast<const f32x4*>(xr + 96));

    float ps = dot4(x0, ws0) + dot4(x1, ws1) + dot4(x2, ws2) + dot4(x3, ws3);
    float pd = dot4(x0, wd0) + dot4(x1, wd1) + dot4(x2, wd2) + dot4(x3, wd3);

    // 3-level butterfly within the 8-lane group
    #pragma unroll
    for (int off = 4; off > 0; off >>= 1) {
        ps += __shfl_xor(ps, off);
        pd += __shfl_xor(pd, off);
    }
    if (sg == 0) {
        proj[n] = ps;
        proj[n_nodes + n] = pd;
    }
}

// K2: 4 edges/thread. Streamed arrays (idx/ew/out) use non-temporal accesses
// so the 400 KB proj gather tables stay L2-resident.
__global__ void __launch_bounds__(BLOCK)
edgeprompt_edges(const int* __restrict__ edge_index,   // [2*E]: [0,E)=src, [E,2E)=dst
                 const float* __restrict__ edge_weight,
                 const float* __restrict__ proj,       // [2*n_nodes]
                 const float* __restrict__ bias_p,
                 float* __restrict__ out,
                 int n_edges, int n_nodes) {
    const int tid = blockIdx.x * blockDim.x + threadIdx.x;
    const float bias = bias_p[0];
    const float* __restrict__ proj_d = proj + n_nodes;

    const int nquads = n_edges >> 2;
    if (tid < nquads) {
        const i32x4 s4 = __builtin_nontemporal_load(
                             reinterpret_cast<const i32x4*>(&edge_index[tid * 4]));
        const i32x4 d4 = __builtin_nontemporal_load(
                             reinterpret_cast<const i32x4*>(&edge_index[n_edges + tid * 4]));
        const f32x4 w4 = __builtin_nontemporal_load(
                             reinterpret_cast<const f32x4*>(&edge_weight[tid * 4]));
        f32x4 o;
        o.x = w4.x / (1.0f + __expf(-(proj[s4.x] + proj_d[d4.x] + bias)));
        o.y = w4.y / (1.0f + __expf(-(proj[s4.y] + proj_d[d4.y] + bias)));
        o.z = w4.z / (1.0f + __expf(-(proj[s4.z] + proj_d[d4.z] + bias)));
        o.w = w4.w / (1.0f + __expf(-(proj[s4.w] + proj_d[d4.w] + bias)));
        __builtin_nontemporal_store(o, reinterpret_cast<f32x4*>(&out[tid * 4]));
    }
    // tail (n_edges % 4), handled by the first few threads
    const int e = (nquads << 2) + tid;
    if (e < n_edges) {
        const int s = edge_index[e];
        const int d = edge_index[n_edges + e];
        out[e] = edge_weight[e] / (1.0f + __expf(-(proj[s] + proj_d[d] + bias)));
    }
}

extern "C" void kernel_launch(void* const* d_in, const int* in_sizes, int n_in,
                              void* d_out, int out_size, void* d_ws, size_t ws_size,
                              hipStream_t stream) {
    // setup_inputs() order: x, edge_index, edge_weight, W, b
    const float* x           = (const float*)d_in[0];
    const int*   edge_index  = (const int*)d_in[1];
    const float* edge_weight = (const float*)d_in[2];
    const float* W           = (const float*)d_in[3];
    const float* b           = (const float*)d_in[4];
    float* out = (float*)d_out;

    const int n_nodes = in_sizes[0] / IN_DIM;   // 50000
    const int n_edges = in_sizes[2];            // 500000
    float* proj = (float*)d_ws;                 // 2*n_nodes floats = 400 KB

    // K1: one-shot, 32 nodes/block (4 waves x 8 nodes).
    const int blocks1 = (n_nodes + 31) / 32;
    edgeprompt_proj<<<blocks1, BLOCK, 0, stream>>>(x, W, proj, n_nodes);

    // K2: 4 edges/thread, one-shot.
    const int blocks2 = ((n_edges + 3) / 4 + BLOCK - 1) / BLOCK;
    edgeprompt_edges<<<blocks2, BLOCK, 0, stream>>>(edge_index, edge_weight, proj, b,
                                                    out, n_edges, n_nodes);
}